// Round 6
// baseline (431.638 us; speedup 1.0000x reference)
//
#include <hip/hip_runtime.h>
#include <math.h>

#define HID 128
#define NGRAPH 4

typedef int idx_t;
typedef short bf16x8 __attribute__((ext_vector_type(8)));
typedef float f32x4 __attribute__((ext_vector_type(4)));
typedef _Float16 f16x8 __attribute__((ext_vector_type(8)));

__device__ inline ushort f2bf(float f) {
  uint u = __float_as_uint(f);
  u += 0x7FFF + ((u >> 16) & 1);   // RNE
  return (ushort)(u >> 16);
}
__device__ inline float bf2f(ushort h) { return __uint_as_float(((uint)h) << 16); }

// swizzled element offset into a [rows][32] ushort LDS tile (16B slots)
__device__ inline int sw(int row, int slot) {
  return (row << 5) + ((slot ^ ((row >> 1) & 3)) << 3);
}

// ---------------- degree histogram ----------------
__global__ __launch_bounds__(256) void k_count(const idx_t* __restrict__ dst,
                                               int* __restrict__ cnt, int E) {
  int e = blockIdx.x * 256 + threadIdx.x;
  if (e < E) atomicAdd(&cnt[dst[e]], 1);
}

// ---------------- hierarchical exclusive scan ----------------
#define SC 1024  // elements per scan block (256 thr x 4)
__global__ __launch_bounds__(256) void k_scan1(const int* __restrict__ cnt,
                                               int* __restrict__ bsum, int n) {
  __shared__ int sh[256];
  int base = blockIdx.x * SC + threadIdx.x * 4;
  int s = 0;
#pragma unroll
  for (int j = 0; j < 4; ++j) { int i = base + j; if (i < n) s += cnt[i]; }
  sh[threadIdx.x] = s;
  __syncthreads();
  for (int o = 128; o > 0; o >>= 1) {
    if (threadIdx.x < o) sh[threadIdx.x] += sh[threadIdx.x + o];
    __syncthreads();
  }
  if (threadIdx.x == 0) bsum[blockIdx.x] = sh[0];
}

__global__ __launch_bounds__(64) void k_scan2(const int* __restrict__ bsum,
                                              int* __restrict__ boff,
                                              int* __restrict__ off, int nb, int n) {
  int lane = threadIdx.x;
  int v = (lane < nb) ? bsum[lane] : 0;
  for (int d = 1; d < 64; d <<= 1) {
    int t = __shfl_up(v, d);
    if (lane >= d) v += t;
  }
  int ex = __shfl_up(v, 1);
  if (lane == 0) ex = 0;
  if (lane < nb) boff[lane] = ex;
  if (lane == nb - 1) off[n] = v;  // grand total
}

__global__ __launch_bounds__(256) void k_scan3(const int* __restrict__ cnt,
                                               const int* __restrict__ boff,
                                               int* __restrict__ off,
                                               float* __restrict__ dinv, int n) {
  __shared__ int sh[256];
  int base = blockIdx.x * SC + threadIdx.x * 4;
  int c[4];
  int s = 0;
#pragma unroll
  for (int j = 0; j < 4; ++j) {
    int i = base + j;
    c[j] = (i < n) ? cnt[i] : 0;
    s += c[j];
  }
  sh[threadIdx.x] = s;
  __syncthreads();
  for (int o = 1; o < 256; o <<= 1) {
    int t = (threadIdx.x >= (unsigned)o) ? sh[threadIdx.x - o] : 0;
    __syncthreads();
    sh[threadIdx.x] += t;
    __syncthreads();
  }
  int ex = sh[threadIdx.x] - s + boff[blockIdx.x];
#pragma unroll
  for (int j = 0; j < 4; ++j) {
    int i = base + j;
    if (i < n) {
      off[i] = ex;
      dinv[i] = 1.0f / sqrtf((float)c[j] + 1.0f);  // deg + self-loop
      ex += c[j];
    }
  }
}

// ---------------- CSR fill: packed (src, weight) per edge ----------------
__global__ __launch_bounds__(256) void k_fill(const idx_t* __restrict__ src,
                                              const idx_t* __restrict__ dst,
                                              const int* __restrict__ off,
                                              const float* __restrict__ dinv,
                                              int* __restrict__ fillc,
                                              int2* __restrict__ edata, int E) {
  int e = blockIdx.x * 256 + threadIdx.x;
  if (e < E) {
    int s = src[e], d = dst[e];
    int p = atomicAdd(&fillc[d], 1);
    float w = dinv[s] * dinv[d];
    edata[off[d] + p] = make_int2(s, __float_as_int(w));
  }
}

// ---------------- W split: fp32 [K][128] -> bf16 hi/lo transposed [128][K] ----
__global__ __launch_bounds__(256) void k_wsplit(const float* __restrict__ W,
                                                ushort* __restrict__ Wh,
                                                ushort* __restrict__ Wl, int K) {
  int i = blockIdx.x * 256 + threadIdx.x;
  if (i >= K * HID) return;
  int k = i >> 7, n = i & 127;
  float f = W[i];
  ushort h = f2bf(f);
  Wh[(size_t)n * K + k] = h;
  Wl[(size_t)n * K + k] = f2bf(f - bf2f(h));
}

// ---------------- split-bf16 MFMA GEMM: Y = X[M][K] @ W[K][128] ------------
// 3-pass hi/lo: Ah*Bh + Ah*Bl + Al*Bh (error ~2^-16 rel).
// KS>1: blockIdx.y picks a K-chunk; writes fp32 partial Ypart[ky][M][128].
// KS==1: writes fp16 Y16 directly.
template <int K, int KS>
__global__ __launch_bounds__(256) void k_gemm_mfma(const float* __restrict__ X,
                                                   const ushort* __restrict__ Wh,
                                                   const ushort* __restrict__ Wl,
                                                   float* __restrict__ Ypart,
                                                   _Float16* __restrict__ Y16,
                                                   int M) {
  __shared__ __align__(16) ushort Ah[128 * 32];
  __shared__ __align__(16) ushort Al[128 * 32];
  __shared__ __align__(16) ushort Bh[128 * 32];
  __shared__ __align__(16) ushort Bl[128 * 32];
  int tid = threadIdx.x;
  int wid = tid >> 6, lane = tid & 63;
  int lrow = lane & 15, kg = lane >> 4;  // frag row/col within 16, k-group 0..3
  int row0 = blockIdx.x * 128;
  constexpr int KC = K / KS;
  int kbase = (KS > 1) ? blockIdx.y * KC : 0;
  f32x4 acc[2][8] = {};

  for (int k0 = kbase; k0 < kbase + KC; k0 += 32) {
    // stage A: 128 rows x 32 k, fp32 -> bf16 hi/lo in registers
#pragma unroll
    for (int p = 0; p < 2; ++p) {
      int g = tid + (p << 8);       // 0..511
      int r = g >> 2, s = g & 3;    // row, 8-elem slot
      int grow = row0 + r;
      float xv[8] = {0.f, 0.f, 0.f, 0.f, 0.f, 0.f, 0.f, 0.f};
      if (grow < M) {
        const float4 v0 = *(const float4*)&X[(size_t)grow * K + k0 + s * 8];
        const float4 v1 = *(const float4*)&X[(size_t)grow * K + k0 + s * 8 + 4];
        xv[0] = v0.x; xv[1] = v0.y; xv[2] = v0.z; xv[3] = v0.w;
        xv[4] = v1.x; xv[5] = v1.y; xv[6] = v1.z; xv[7] = v1.w;
      }
      bf16x8 hv, lv;
#pragma unroll
      for (int j = 0; j < 8; ++j) {
        ushort hb = f2bf(xv[j]);
        hv[j] = (short)hb;
        lv[j] = (short)f2bf(xv[j] - bf2f(hb));
      }
      *(bf16x8*)&Ah[sw(r, s)] = hv;
      *(bf16x8*)&Al[sw(r, s)] = lv;
    }
    // stage B: 128 cols x 32 k from pre-split transposed W (bf16)
#pragma unroll
    for (int p = 0; p < 2; ++p) {
      int g = tid + (p << 8);
      int c = g >> 2, s = g & 3;
      *(bf16x8*)&Bh[sw(c, s)] = *(const bf16x8*)&Wh[(size_t)c * K + k0 + s * 8];
      *(bf16x8*)&Bl[sw(c, s)] = *(const bf16x8*)&Wl[(size_t)c * K + k0 + s * 8];
    }
    __syncthreads();

    bf16x8 ah[2], al[2];
#pragma unroll
    for (int mi = 0; mi < 2; ++mi) {
      int r = wid * 32 + mi * 16 + lrow;
      ah[mi] = *(const bf16x8*)&Ah[sw(r, kg)];
      al[mi] = *(const bf16x8*)&Al[sw(r, kg)];
    }
#pragma unroll
    for (int ni = 0; ni < 8; ++ni) {
      int c = ni * 16 + lrow;
      bf16x8 bh = *(const bf16x8*)&Bh[sw(c, kg)];
      bf16x8 bl = *(const bf16x8*)&Bl[sw(c, kg)];
#pragma unroll
      for (int mi = 0; mi < 2; ++mi) {
        acc[mi][ni] = __builtin_amdgcn_mfma_f32_16x16x32_bf16(ah[mi], bh, acc[mi][ni], 0, 0, 0);
        acc[mi][ni] = __builtin_amdgcn_mfma_f32_16x16x32_bf16(al[mi], bh, acc[mi][ni], 0, 0, 0);
        acc[mi][ni] = __builtin_amdgcn_mfma_f32_16x16x32_bf16(ah[mi], bl, acc[mi][ni], 0, 0, 0);
      }
    }
    __syncthreads();
  }
  // epilogue: C frag row=(lane>>4)*4+reg, col=lane&15
  if (KS > 1) {
    float* yp = Ypart + (size_t)blockIdx.y * M * HID;
#pragma unroll
    for (int mi = 0; mi < 2; ++mi)
#pragma unroll
      for (int ni = 0; ni < 8; ++ni)
#pragma unroll
        for (int r = 0; r < 4; ++r) {
          int grow = row0 + wid * 32 + mi * 16 + kg * 4 + r;
          if (grow < M) yp[(size_t)grow * HID + ni * 16 + lrow] = acc[mi][ni][r];
        }
  } else {
#pragma unroll
    for (int mi = 0; mi < 2; ++mi)
#pragma unroll
      for (int ni = 0; ni < 8; ++ni)
#pragma unroll
        for (int r = 0; r < 4; ++r) {
          int grow = row0 + wid * 32 + mi * 16 + kg * 4 + r;
          if (grow < M)
            Y16[(size_t)grow * HID + ni * 16 + lrow] = (_Float16)acc[mi][ni][r];
        }
  }
}

// ---------------- split-K reduce + fp16 convert ----------------
__global__ __launch_bounds__(256) void k_red(const float* __restrict__ part,
                                             _Float16* __restrict__ o16,
                                             size_t total) {
  size_t i = ((size_t)blockIdx.x * 256 + threadIdx.x) * 4;
  if (i >= total) return;
  float4 a = *(const float4*)&part[i];
  float4 b = *(const float4*)&part[i + total];
  float4 c = *(const float4*)&part[i + 2 * total];
  float4 d = *(const float4*)&part[i + 3 * total];
  _Float16 r[4];
  r[0] = (_Float16)(a.x + b.x + c.x + d.x);
  r[1] = (_Float16)(a.y + b.y + c.y + d.y);
  r[2] = (_Float16)(a.z + b.z + c.z + d.z);
  r[3] = (_Float16)(a.w + b.w + c.w + d.w);
  *(short4*)&o16[i] = *(short4*)r;
}

// ---------------- gather-aggregate (fp16) + bias + ReLU --------------------
// One wave per node. 4 groups of 16 lanes; group g strides the neighbor list
// by 4, each lane loading 8 fp16 features (16 B). fp32 accumulate.
__global__ __launch_bounds__(256) void k_agg16(const _Float16* __restrict__ xh,
                                               const float* __restrict__ dinv,
                                               const int* __restrict__ off,
                                               const int2* __restrict__ edata,
                                               const float* __restrict__ bias,
                                               float* __restrict__ hout, int n) {
  int v = blockIdx.x * 4 + (threadIdx.x >> 6);
  if (v >= n) return;
  int lane = threadIdx.x & 63;
  int grp = lane >> 4, gl = lane & 15;
  int fb = gl * 8;                       // this lane's 8 features
  float acc[8] = {0.f, 0.f, 0.f, 0.f, 0.f, 0.f, 0.f, 0.f};
  int j0 = off[v], j1 = off[v + 1];
  for (int j = j0 + grp; j < j1; j += 4) {
    int2 e = edata[j];
    float w = __int_as_float(e.y);
    f16x8 m = *(const f16x8*)&xh[(size_t)e.x * HID + fb];
#pragma unroll
    for (int q = 0; q < 8; ++q) acc[q] = fmaf(w, (float)m[q], acc[q]);
  }
  // combine the 4 groups (feature layout identical across groups)
#pragma unroll
  for (int q = 0; q < 8; ++q) {
    acc[q] += __shfl_xor(acc[q], 16);
    acc[q] += __shfl_xor(acc[q], 32);
  }
  if (grp == 0) {
    float dv = dinv[v], dv2 = dv * dv;
    f16x8 sv = *(const f16x8*)&xh[(size_t)v * HID + fb];
    const float4 b0 = *(const float4*)&bias[fb];
    const float4 b1 = *(const float4*)&bias[fb + 4];
    float4 o0, o1;
    o0.x = fmaxf(fmaf(dv2, (float)sv[0], acc[0]) + b0.x, 0.f);
    o0.y = fmaxf(fmaf(dv2, (float)sv[1], acc[1]) + b0.y, 0.f);
    o0.z = fmaxf(fmaf(dv2, (float)sv[2], acc[2]) + b0.z, 0.f);
    o0.w = fmaxf(fmaf(dv2, (float)sv[3], acc[3]) + b0.w, 0.f);
    o1.x = fmaxf(fmaf(dv2, (float)sv[4], acc[4]) + b1.x, 0.f);
    o1.y = fmaxf(fmaf(dv2, (float)sv[5], acc[5]) + b1.y, 0.f);
    o1.z = fmaxf(fmaf(dv2, (float)sv[6], acc[6]) + b1.z, 0.f);
    o1.w = fmaxf(fmaf(dv2, (float)sv[7], acc[7]) + b1.w, 0.f);
    *(float4*)&hout[(size_t)v * HID + fb] = o0;
    *(float4*)&hout[(size_t)v * HID + fb + 4] = o1;
  }
}

// ---------------- per-graph node counts ----------------
__global__ __launch_bounds__(256) void k_gcnt(const idx_t* __restrict__ batch,
                                              int* __restrict__ gcnt, int n) {
  __shared__ int h[NGRAPH];
  int tid = threadIdx.x;
  if (tid < NGRAPH) h[tid] = 0;
  __syncthreads();
  int i = blockIdx.x * 256 + tid;
  if (i < n) atomicAdd(&h[batch[i]], 1);
  __syncthreads();
  if (tid < NGRAPH && h[tid]) atomicAdd(&gcnt[tid], h[tid]);
}

// ---------------- segment max+sum pooling (batch sorted) ----------------
__global__ __launch_bounds__(128) void k_pool(const float* __restrict__ h,
                                              const idx_t* __restrict__ batch,
                                              float* __restrict__ gmax,
                                              float* __restrict__ gsum, int n) {
  int f = threadIdx.x;
  int v0 = blockIdx.x * 128;
  int cur = -1;
  float mx = 0.f, sm = 0.f;
  for (int i = 0; i < 128; ++i) {
    int v = v0 + i;
    if (v >= n) break;
    int g = batch[v];
    if (g != cur) {
      if (cur >= 0) {
        atomicMax((int*)&gmax[cur * HID + f], __float_as_int(mx));  // h>=0
        atomicAdd(&gsum[cur * HID + f], sm);
      }
      cur = g; mx = 0.f; sm = 0.f;
    }
    float val = h[(size_t)v * HID + f];
    mx = fmaxf(mx, val);
    sm += val;
  }
  if (cur >= 0) {
    atomicMax((int*)&gmax[cur * HID + f], __float_as_int(mx));
    atomicAdd(&gsum[cur * HID + f], sm);
  }
}

// ---------------- tiny MLP head (one block) ----------------
__global__ __launch_bounds__(256) void k_mlp(const float* __restrict__ gmax,
                                             const float* __restrict__ gsum,
                                             const int* __restrict__ gcnt,
                                             const float* __restrict__ Wl1,
                                             const float* __restrict__ bl1,
                                             const float* __restrict__ Wl2,
                                             const float* __restrict__ bl2,
                                             const float* __restrict__ Wl3,
                                             const float* __restrict__ bl3,
                                             float* __restrict__ out) {
  __shared__ float G[NGRAPH][2 * HID];
  __shared__ float H1[NGRAPH][HID];
  __shared__ float H2[NGRAPH][HID / 2];
  int t = threadIdx.x;
  for (int i = t; i < NGRAPH * 2 * HID; i += 256) {
    int gi = i >> 8, j = i & 255;
    float val;
    if (j < HID) val = gmax[gi * HID + j];
    else val = gsum[gi * HID + (j - HID)] / fmaxf((float)gcnt[gi], 1.0f);
    G[gi][j] = val;
  }
  __syncthreads();
  for (int i = t; i < NGRAPH * HID; i += 256) {
    int gi = i >> 7, j = i & 127;
    float a = bl1[j];
    for (int k = 0; k < 2 * HID; ++k) a = fmaf(G[gi][k], Wl1[k * HID + j], a);
    H1[gi][j] = fmaxf(a, 0.f);
  }
  __syncthreads();
  {
    int gi = t >> 6, j = t & 63;
    float a = bl2[j];
    for (int k = 0; k < HID; ++k) a = fmaf(H1[gi][k], Wl2[k * 64 + j], a);
    H2[gi][j] = fmaxf(a, 0.f);
  }
  __syncthreads();
  if (t < NGRAPH) {
    float a = bl3[0];
    for (int k = 0; k < 64; ++k) a = fmaf(H2[t][k], Wl3[k], a);
    out[t] = fminf(a, 5.0f);
  }
}

extern "C" void kernel_launch(void* const* d_in, const int* in_sizes, int n_in,
                              void* d_out, int out_size, void* d_ws, size_t ws_size,
                              hipStream_t stream) {
  const float* x   = (const float*)d_in[0];
  const idx_t* ei  = (const idx_t*)d_in[1];
  const idx_t* bat = (const idx_t*)d_in[2];
  const float* W0 = (const float*)d_in[3];  const float* b0 = (const float*)d_in[4];
  const float* W1 = (const float*)d_in[5];  const float* b1 = (const float*)d_in[6];
  const float* W2 = (const float*)d_in[7];  const float* b2 = (const float*)d_in[8];
  const float* Wl1 = (const float*)d_in[9];  const float* bl1 = (const float*)d_in[10];
  const float* Wl2 = (const float*)d_in[11]; const float* bl2 = (const float*)d_in[12];
  const float* Wl3 = (const float*)d_in[13]; const float* bl3 = (const float*)d_in[14];
  float* out = (float*)d_out;

  const int N = in_sizes[2];
  const int E = in_sizes[1] / 2;
  const idx_t* srcv = ei;
  const idx_t* dstv = ei + E;
  const int nb = (N + SC - 1) / SC;  // 49 scan blocks (<=64)

  char* ws = (char*)d_ws;
  size_t o = 0;
  auto alloc = [&](size_t bytes) -> void* {
    void* p = ws + o;
    o = (o + bytes + 255) & ~(size_t)255;
    return p;
  };
  _Float16* xh   = (_Float16*)alloc((size_t)N * HID * 2);  // xw / h_in fp16
  float* bufB    = (float*)alloc((size_t)N * HID * 4);     // agg out fp32
  float* part    = (float*)alloc((size_t)4 * N * HID * 4); // split-K partials
  float* dinv = (float*)alloc((size_t)N * 4);
  int* cnt    = (int*)alloc((size_t)N * 4);
  int* off    = (int*)alloc((size_t)(N + 1) * 4);
  int* fillc  = (int*)alloc((size_t)N * 4);
  int2* edata = (int2*)alloc((size_t)E * 8);
  int* bsum   = (int*)alloc(64 * 4);
  int* boff   = (int*)alloc(64 * 4);
  ushort* Wh0 = (ushort*)alloc((size_t)1024 * HID * 2);
  ushort* Wl0 = (ushort*)alloc((size_t)1024 * HID * 2);
  ushort* Wh1 = (ushort*)alloc((size_t)HID * HID * 2);
  ushort* Wlo1 = (ushort*)alloc((size_t)HID * HID * 2);
  ushort* Wh2 = (ushort*)alloc((size_t)HID * HID * 2);
  ushort* Wlo2 = (ushort*)alloc((size_t)HID * HID * 2);
  float* gmax = (float*)alloc(NGRAPH * HID * 4);
  float* gsum = (float*)alloc(NGRAPH * HID * 4);
  int* gcnt   = (int*)alloc(NGRAPH * 4);

  hipMemsetAsync(cnt, 0, (size_t)N * 4, stream);
  hipMemsetAsync(fillc, 0, (size_t)N * 4, stream);
  hipMemsetAsync(gmax, 0, NGRAPH * HID * 4, stream);
  hipMemsetAsync(gsum, 0, NGRAPH * HID * 4, stream);
  hipMemsetAsync(gcnt, 0, NGRAPH * 4, stream);

  // weight splits (tiny)
  k_wsplit<<<(1024 * HID + 255) / 256, 256, 0, stream>>>(W0, Wh0, Wl0, 1024);
  k_wsplit<<<(HID * HID + 255) / 256, 256, 0, stream>>>(W1, Wh1, Wlo1, HID);
  k_wsplit<<<(HID * HID + 255) / 256, 256, 0, stream>>>(W2, Wh2, Wlo2, HID);

  // CSR build
  k_count<<<(E + 255) / 256, 256, 0, stream>>>(dstv, cnt, E);
  k_scan1<<<nb, 256, 0, stream>>>(cnt, bsum, N);
  k_scan2<<<1, 64, 0, stream>>>(bsum, boff, off, nb, N);
  k_scan3<<<nb, 256, 0, stream>>>(cnt, boff, off, dinv, N);
  k_fill<<<(E + 255) / 256, 256, 0, stream>>>(srcv, dstv, off, dinv, fillc, edata, E);

  const int gblk = (N + 127) / 128;
  const int ablk = (N + 3) / 4;
  const size_t total = (size_t)N * HID;
  // layer 0: 1024 -> 128, split-K=4 + reduce
  k_gemm_mfma<1024, 4><<<dim3(gblk, 4), 256, 0, stream>>>(x, Wh0, Wl0, part, nullptr, N);
  k_red<<<(int)((total / 4 + 255) / 256), 256, 0, stream>>>(part, xh, total);
  k_agg16<<<ablk, 256, 0, stream>>>(xh, dinv, off, edata, b0, bufB, N);
  // layer 1
  k_gemm_mfma<HID, 1><<<gblk, 256, 0, stream>>>(bufB, Wh1, Wlo1, nullptr, xh, N);
  k_agg16<<<ablk, 256, 0, stream>>>(xh, dinv, off, edata, b1, bufB, N);
  // layer 2
  k_gemm_mfma<HID, 1><<<gblk, 256, 0, stream>>>(bufB, Wh2, Wlo2, nullptr, xh, N);
  k_agg16<<<ablk, 256, 0, stream>>>(xh, dinv, off, edata, b2, bufB, N);

  // pooling + head
  k_gcnt<<<(N + 255) / 256, 256, 0, stream>>>(bat, gcnt, N);
  k_pool<<<(N + 127) / 128, 128, 0, stream>>>(bufB, bat, gmax, gsum, N);
  k_mlp<<<1, 256, 0, stream>>>(gmax, gsum, gcnt, Wl1, bl1, Wl2, bl2, Wl3, bl3, out);
}

// Round 7
// 391.734 us; speedup vs baseline: 1.1019x; 1.1019x over previous
//
#include <hip/hip_runtime.h>
#include <math.h>

#define HID 128
#define NGRAPH 4

typedef int idx_t;
typedef short bf16x8 __attribute__((ext_vector_type(8)));
typedef float f32x4 __attribute__((ext_vector_type(4)));
typedef _Float16 f16x8 __attribute__((ext_vector_type(8)));
typedef unsigned short u16x8 __attribute__((ext_vector_type(8)));

__device__ inline ushort f2bf(float f) {
  uint u = __float_as_uint(f);
  u += 0x7FFF + ((u >> 16) & 1);   // RNE
  return (ushort)(u >> 16);
}
__device__ inline float bf2f(ushort h) { return __uint_as_float(((uint)h) << 16); }

// swizzled element offset into a [rows][32] ushort LDS tile (16B slots)
__device__ inline int sw(int row, int slot) {
  return (row << 5) + ((slot ^ ((row >> 1) & 3)) << 3);
}

// ---------------- degree histogram ----------------
__global__ __launch_bounds__(256) void k_count(const idx_t* __restrict__ dst,
                                               int* __restrict__ cnt, int E) {
  int e = blockIdx.x * 256 + threadIdx.x;
  if (e < E) atomicAdd(&cnt[dst[e]], 1);
}

// ---------------- hierarchical exclusive scan ----------------
#define SC 1024  // elements per scan block (256 thr x 4)
__global__ __launch_bounds__(256) void k_scan1(const int* __restrict__ cnt,
                                               int* __restrict__ bsum, int n) {
  __shared__ int sh[256];
  int base = blockIdx.x * SC + threadIdx.x * 4;
  int s = 0;
#pragma unroll
  for (int j = 0; j < 4; ++j) { int i = base + j; if (i < n) s += cnt[i]; }
  sh[threadIdx.x] = s;
  __syncthreads();
  for (int o = 128; o > 0; o >>= 1) {
    if (threadIdx.x < o) sh[threadIdx.x] += sh[threadIdx.x + o];
    __syncthreads();
  }
  if (threadIdx.x == 0) bsum[blockIdx.x] = sh[0];
}

__global__ __launch_bounds__(64) void k_scan2(const int* __restrict__ bsum,
                                              int* __restrict__ boff,
                                              int* __restrict__ off, int nb, int n) {
  int lane = threadIdx.x;
  int v = (lane < nb) ? bsum[lane] : 0;
  for (int d = 1; d < 64; d <<= 1) {
    int t = __shfl_up(v, d);
    if (lane >= d) v += t;
  }
  int ex = __shfl_up(v, 1);
  if (lane == 0) ex = 0;
  if (lane < nb) boff[lane] = ex;
  if (lane == nb - 1) off[n] = v;  // grand total
}

__global__ __launch_bounds__(256) void k_scan3(const int* __restrict__ cnt,
                                               const int* __restrict__ boff,
                                               int* __restrict__ off,
                                               float* __restrict__ dinv, int n) {
  __shared__ int sh[256];
  int base = blockIdx.x * SC + threadIdx.x * 4;
  int c[4];
  int s = 0;
#pragma unroll
  for (int j = 0; j < 4; ++j) {
    int i = base + j;
    c[j] = (i < n) ? cnt[i] : 0;
    s += c[j];
  }
  sh[threadIdx.x] = s;
  __syncthreads();
  for (int o = 1; o < 256; o <<= 1) {
    int t = (threadIdx.x >= (unsigned)o) ? sh[threadIdx.x - o] : 0;
    __syncthreads();
    sh[threadIdx.x] += t;
    __syncthreads();
  }
  int ex = sh[threadIdx.x] - s + boff[blockIdx.x];
#pragma unroll
  for (int j = 0; j < 4; ++j) {
    int i = base + j;
    if (i < n) {
      off[i] = ex;
      dinv[i] = 1.0f / sqrtf((float)c[j] + 1.0f);  // deg + self-loop
      ex += c[j];
    }
  }
}

// ---------------- CSR fill: packed (src, weight) per edge ----------------
__global__ __launch_bounds__(256) void k_fill(const idx_t* __restrict__ src,
                                              const idx_t* __restrict__ dst,
                                              const int* __restrict__ off,
                                              const float* __restrict__ dinv,
                                              int* __restrict__ fillc,
                                              int2* __restrict__ edata, int E) {
  int e = blockIdx.x * 256 + threadIdx.x;
  if (e < E) {
    int s = src[e], d = dst[e];
    int p = atomicAdd(&fillc[d], 1);
    float w = dinv[s] * dinv[d];
    edata[off[d] + p] = make_int2(s, __float_as_int(w));
  }
}

// ---------------- W split: fp32 [K][128] -> bf16 hi/lo transposed [128][K] ----
__global__ __launch_bounds__(256) void k_wsplit(const float* __restrict__ W,
                                                ushort* __restrict__ Wh,
                                                ushort* __restrict__ Wl, int K) {
  int i = blockIdx.x * 256 + threadIdx.x;
  if (i >= K * HID) return;
  int k = i >> 7, n = i & 127;
  float f = W[i];
  ushort h = f2bf(f);
  Wh[(size_t)n * K + k] = h;
  Wl[(size_t)n * K + k] = f2bf(f - bf2f(h));
}

// ---------------- pipelined split-bf16 MFMA GEMM ---------------------------
// Y16[M][128] = X[M][K] @ W[K][128], 3-pass hi/lo (err ~2^-16 rel).
// A: direct global->reg (wave-private rows; never in LDS), prefetched.
// B: double-buffered LDS, staged via reg one K-step ahead. 1 barrier/step.
template <int K>
__global__ __launch_bounds__(256) void k_gemm2(const float* __restrict__ X,
                                               const ushort* __restrict__ Wh,
                                               const ushort* __restrict__ Wl,
                                               _Float16* __restrict__ Y16, int M) {
  __shared__ __align__(16) ushort BhL[2][128 * 32];
  __shared__ __align__(16) ushort BlL[2][128 * 32];
  const int tid = threadIdx.x;
  const int wid = tid >> 6, lane = tid & 63;
  const int lrow = lane & 15, kg = lane >> 4;
  const int row0 = blockIdx.x * 128;
  const int r0 = row0 + wid * 32 + lrow;   // mi=0 row for this lane
  const int r1 = r0 + 16;                  // mi=1 row
  const bool ok0 = r0 < M, ok1 = r1 < M;
  const float* xp0 = X + (size_t)(ok0 ? r0 : 0) * K + kg * 8;
  const float* xp1 = X + (size_t)(ok1 ? r1 : 0) * K + kg * 8;
  // B staging addresses: thread covers two 16B chunks per (hi|lo)
  const int c0 = tid >> 2, s0 = tid & 3;
  const int c1 = (tid + 256) >> 2, s1 = tid & 3;
  const ushort* wh0 = Wh + (size_t)c0 * K + s0 * 8;
  const ushort* wh1 = Wh + (size_t)c1 * K + s1 * 8;
  const ushort* wl0 = Wl + (size_t)c0 * K + s0 * 8;
  const ushort* wl1 = Wl + (size_t)c1 * K + s1 * 8;
  const int d0 = sw(c0, s0), d1 = sw(c1, s1);

  f32x4 acc[2][8] = {};
  float4 aA0, aA1, aA2, aA3, aB0, aB1, aB2, aB3;   // A regs, two K-steps
  u16x8 bA0, bA1, bA2, bA3, bB0, bB1, bB2, bB3;    // B staging regs

#define LOAD_A(k0, a0, a1, a2, a3)                                        \
  {                                                                       \
    a0 = ok0 ? *(const float4*)(xp0 + (k0)) : make_float4(0, 0, 0, 0);    \
    a1 = ok0 ? *(const float4*)(xp0 + (k0) + 4) : make_float4(0, 0, 0, 0);\
    a2 = ok1 ? *(const float4*)(xp1 + (k0)) : make_float4(0, 0, 0, 0);    \
    a3 = ok1 ? *(const float4*)(xp1 + (k0) + 4) : make_float4(0, 0, 0, 0);\
  }
#define LOAD_B(k0, b0, b1, b2, b3)                                        \
  {                                                                       \
    b0 = *(const u16x8*)(wh0 + (k0)); b1 = *(const u16x8*)(wh1 + (k0));   \
    b2 = *(const u16x8*)(wl0 + (k0)); b3 = *(const u16x8*)(wl1 + (k0));   \
  }
#define WRITE_B(buf, b0, b1, b2, b3)                                      \
  {                                                                       \
    *(u16x8*)&BhL[buf][d0] = b0; *(u16x8*)&BhL[buf][d1] = b1;             \
    *(u16x8*)&BlL[buf][d0] = b2; *(u16x8*)&BlL[buf][d1] = b3;             \
  }
#define CONV8(v0, v1, hdst, ldst)                                         \
  {                                                                       \
    float tf[8] = {v0.x, v0.y, v0.z, v0.w, v1.x, v1.y, v1.z, v1.w};       \
    _Pragma("unroll")                                                     \
    for (int j = 0; j < 8; ++j) {                                         \
      ushort hb = f2bf(tf[j]);                                            \
      hdst[j] = (short)hb;                                                \
      ldst[j] = (short)f2bf(tf[j] - bf2f(hb));                            \
    }                                                                     \
  }
#define MFMA_STEP(buf, ah0, al0, ah1, al1)                                \
  {                                                                       \
    _Pragma("unroll")                                                     \
    for (int ni = 0; ni < 8; ++ni) {                                      \
      int c = ni * 16 + lrow;                                             \
      bf16x8 bh = *(const bf16x8*)&BhL[buf][sw(c, kg)];                   \
      bf16x8 bl = *(const bf16x8*)&BlL[buf][sw(c, kg)];                   \
      acc[0][ni] = __builtin_amdgcn_mfma_f32_16x16x32_bf16(ah0, bh, acc[0][ni], 0, 0, 0); \
      acc[0][ni] = __builtin_amdgcn_mfma_f32_16x16x32_bf16(al0, bh, acc[0][ni], 0, 0, 0); \
      acc[0][ni] = __builtin_amdgcn_mfma_f32_16x16x32_bf16(ah0, bl, acc[0][ni], 0, 0, 0); \
      acc[1][ni] = __builtin_amdgcn_mfma_f32_16x16x32_bf16(ah1, bh, acc[1][ni], 0, 0, 0); \
      acc[1][ni] = __builtin_amdgcn_mfma_f32_16x16x32_bf16(al1, bh, acc[1][ni], 0, 0, 0); \
      acc[1][ni] = __builtin_amdgcn_mfma_f32_16x16x32_bf16(ah1, bl, acc[1][ni], 0, 0, 0); \
    }                                                                     \
  }

  // prologue: stage step 0 into buf0, issue step-1 loads across the barrier
  LOAD_A(0, aA0, aA1, aA2, aA3);
  LOAD_B(0, bA0, bA1, bA2, bA3);
  WRITE_B(0, bA0, bA1, bA2, bA3);
  if (K > 32) {
    LOAD_A(32, aB0, aB1, aB2, aB3);
    LOAD_B(32, bB0, bB1, bB2, bB3);
  }
  __syncthreads();

  for (int k0 = 0; k0 < K; k0 += 64) {
    {  // even sub-step: compute buf0 (k0); stage k0+32 -> buf1
      if (k0 + 32 < K) WRITE_B(1, bB0, bB1, bB2, bB3);
      bf16x8 ah0, al0, ah1, al1;
      CONV8(aA0, aA1, ah0, al0);
      CONV8(aA2, aA3, ah1, al1);
      if (k0 + 64 < K) {
        LOAD_A(k0 + 64, aA0, aA1, aA2, aA3);
        LOAD_B(k0 + 64, bA0, bA1, bA2, bA3);
      }
      MFMA_STEP(0, ah0, al0, ah1, al1);
      __syncthreads();
    }
    if (k0 + 32 >= K) break;
    {  // odd sub-step: compute buf1 (k0+32); stage k0+64 -> buf0
      if (k0 + 96 < K) WRITE_B(0, bA0, bA1, bA2, bA3);
      bf16x8 ah0, al0, ah1, al1;
      CONV8(aB0, aB1, ah0, al0);
      CONV8(aB2, aB3, ah1, al1);
      if (k0 + 96 < K) {
        LOAD_A(k0 + 96, aB0, aB1, aB2, aB3);
        LOAD_B(k0 + 96, bB0, bB1, bB2, bB3);
      }
      MFMA_STEP(1, ah0, al0, ah1, al1);
      __syncthreads();
    }
  }
  // epilogue: C frag row=(lane>>4)*4+reg, col=lane&15; fp16 out
#pragma unroll
  for (int mi = 0; mi < 2; ++mi)
#pragma unroll
    for (int ni = 0; ni < 8; ++ni)
#pragma unroll
      for (int r = 0; r < 4; ++r) {
        int grow = row0 + wid * 32 + mi * 16 + kg * 4 + r;
        if (grow < M)
          Y16[(size_t)grow * HID + ni * 16 + lrow] = (_Float16)acc[mi][ni][r];
      }
#undef LOAD_A
#undef LOAD_B
#undef WRITE_B
#undef CONV8
#undef MFMA_STEP
}

// ---------------- gather-aggregate (fp16) + bias + ReLU --------------------
__global__ __launch_bounds__(256) void k_agg16(const _Float16* __restrict__ xh,
                                               const float* __restrict__ dinv,
                                               const int* __restrict__ off,
                                               const int2* __restrict__ edata,
                                               const float* __restrict__ bias,
                                               float* __restrict__ hout, int n) {
  int v = blockIdx.x * 4 + (threadIdx.x >> 6);
  if (v >= n) return;
  int lane = threadIdx.x & 63;
  int grp = lane >> 4, gl = lane & 15;
  int fb = gl * 8;                       // this lane's 8 features
  float acc[8] = {0.f, 0.f, 0.f, 0.f, 0.f, 0.f, 0.f, 0.f};
  int j0 = off[v], j1 = off[v + 1];
  for (int j = j0 + grp; j < j1; j += 4) {
    int2 e = edata[j];
    float w = __int_as_float(e.y);
    f16x8 m = *(const f16x8*)&xh[(size_t)e.x * HID + fb];
#pragma unroll
    for (int q = 0; q < 8; ++q) acc[q] = fmaf(w, (float)m[q], acc[q]);
  }
#pragma unroll
  for (int q = 0; q < 8; ++q) {
    acc[q] += __shfl_xor(acc[q], 16);
    acc[q] += __shfl_xor(acc[q], 32);
  }
  if (grp == 0) {
    float dv = dinv[v], dv2 = dv * dv;
    f16x8 sv = *(const f16x8*)&xh[(size_t)v * HID + fb];
    const float4 b0 = *(const float4*)&bias[fb];
    const float4 b1 = *(const float4*)&bias[fb + 4];
    float4 o0, o1;
    o0.x = fmaxf(fmaf(dv2, (float)sv[0], acc[0]) + b0.x, 0.f);
    o0.y = fmaxf(fmaf(dv2, (float)sv[1], acc[1]) + b0.y, 0.f);
    o0.z = fmaxf(fmaf(dv2, (float)sv[2], acc[2]) + b0.z, 0.f);
    o0.w = fmaxf(fmaf(dv2, (float)sv[3], acc[3]) + b0.w, 0.f);
    o1.x = fmaxf(fmaf(dv2, (float)sv[4], acc[4]) + b1.x, 0.f);
    o1.y = fmaxf(fmaf(dv2, (float)sv[5], acc[5]) + b1.y, 0.f);
    o1.z = fmaxf(fmaf(dv2, (float)sv[6], acc[6]) + b1.z, 0.f);
    o1.w = fmaxf(fmaf(dv2, (float)sv[7], acc[7]) + b1.w, 0.f);
    *(float4*)&hout[(size_t)v * HID + fb] = o0;
    *(float4*)&hout[(size_t)v * HID + fb + 4] = o1;
  }
}

// ---------------- per-graph node counts ----------------
__global__ __launch_bounds__(256) void k_gcnt(const idx_t* __restrict__ batch,
                                              int* __restrict__ gcnt, int n) {
  __shared__ int h[NGRAPH];
  int tid = threadIdx.x;
  if (tid < NGRAPH) h[tid] = 0;
  __syncthreads();
  int i = blockIdx.x * 256 + tid;
  if (i < n) atomicAdd(&h[batch[i]], 1);
  __syncthreads();
  if (tid < NGRAPH && h[tid]) atomicAdd(&gcnt[tid], h[tid]);
}

// ---------------- segment max+sum pooling (batch sorted) ----------------
__global__ __launch_bounds__(128) void k_pool(const float* __restrict__ h,
                                              const idx_t* __restrict__ batch,
                                              float* __restrict__ gmax,
                                              float* __restrict__ gsum, int n) {
  int f = threadIdx.x;
  int v0 = blockIdx.x * 128;
  int cur = -1;
  float mx = 0.f, sm = 0.f;
  for (int i = 0; i < 128; ++i) {
    int v = v0 + i;
    if (v >= n) break;
    int g = batch[v];
    if (g != cur) {
      if (cur >= 0) {
        atomicMax((int*)&gmax[cur * HID + f], __float_as_int(mx));  // h>=0
        atomicAdd(&gsum[cur * HID + f], sm);
      }
      cur = g; mx = 0.f; sm = 0.f;
    }
    float val = h[(size_t)v * HID + f];
    mx = fmaxf(mx, val);
    sm += val;
  }
  if (cur >= 0) {
    atomicMax((int*)&gmax[cur * HID + f], __float_as_int(mx));
    atomicAdd(&gsum[cur * HID + f], sm);
  }
}

// ---------------- tiny MLP head (one block) ----------------
__global__ __launch_bounds__(256) void k_mlp(const float* __restrict__ gmax,
                                             const float* __restrict__ gsum,
                                             const int* __restrict__ gcnt,
                                             const float* __restrict__ Wl1,
                                             const float* __restrict__ bl1,
                                             const float* __restrict__ Wl2,
                                             const float* __restrict__ bl2,
                                             const float* __restrict__ Wl3,
                                             const float* __restrict__ bl3,
                                             float* __restrict__ out) {
  __shared__ float G[NGRAPH][2 * HID];
  __shared__ float H1[NGRAPH][HID];
  __shared__ float H2[NGRAPH][HID / 2];
  int t = threadIdx.x;
  for (int i = t; i < NGRAPH * 2 * HID; i += 256) {
    int gi = i >> 8, j = i & 255;
    float val;
    if (j < HID) val = gmax[gi * HID + j];
    else val = gsum[gi * HID + (j - HID)] / fmaxf((float)gcnt[gi], 1.0f);
    G[gi][j] = val;
  }
  __syncthreads();
  for (int i = t; i < NGRAPH * HID; i += 256) {
    int gi = i >> 7, j = i & 127;
    float a = bl1[j];
    for (int k = 0; k < 2 * HID; ++k) a = fmaf(G[gi][k], Wl1[k * HID + j], a);
    H1[gi][j] = fmaxf(a, 0.f);
  }
  __syncthreads();
  {
    int gi = t >> 6, j = t & 63;
    float a = bl2[j];
    for (int k = 0; k < HID; ++k) a = fmaf(H1[gi][k], Wl2[k * 64 + j], a);
    H2[gi][j] = fmaxf(a, 0.f);
  }
  __syncthreads();
  if (t < NGRAPH) {
    float a = bl3[0];
    for (int k = 0; k < 64; ++k) a = fmaf(H2[t][k], Wl3[k], a);
    out[t] = fminf(a, 5.0f);
  }
}

extern "C" void kernel_launch(void* const* d_in, const int* in_sizes, int n_in,
                              void* d_out, int out_size, void* d_ws, size_t ws_size,
                              hipStream_t stream) {
  const float* x   = (const float*)d_in[0];
  const idx_t* ei  = (const idx_t*)d_in[1];
  const idx_t* bat = (const idx_t*)d_in[2];
  const float* W0 = (const float*)d_in[3];  const float* b0 = (const float*)d_in[4];
  const float* W1 = (const float*)d_in[5];  const float* b1 = (const float*)d_in[6];
  const float* W2 = (const float*)d_in[7];  const float* b2 = (const float*)d_in[8];
  const float* Wl1 = (const float*)d_in[9];  const float* bl1 = (const float*)d_in[10];
  const float* Wl2 = (const float*)d_in[11]; const float* bl2 = (const float*)d_in[12];
  const float* Wl3 = (const float*)d_in[13]; const float* bl3 = (const float*)d_in[14];
  float* out = (float*)d_out;

  const int N = in_sizes[2];
  const int E = in_sizes[1] / 2;
  const idx_t* srcv = ei;
  const idx_t* dstv = ei + E;
  const int nb = (N + SC - 1) / SC;  // 49 scan blocks (<=64)

  char* ws = (char*)d_ws;
  size_t o = 0;
  auto alloc = [&](size_t bytes) -> void* {
    void* p = ws + o;
    o = (o + bytes + 255) & ~(size_t)255;
    return p;
  };
  _Float16* xh   = (_Float16*)alloc((size_t)N * HID * 2);  // xw / h_in fp16
  float* bufB    = (float*)alloc((size_t)N * HID * 4);     // agg out fp32
  float* dinv = (float*)alloc((size_t)N * 4);
  int* cnt    = (int*)alloc((size_t)N * 4);
  int* off    = (int*)alloc((size_t)(N + 1) * 4);
  int* fillc  = (int*)alloc((size_t)N * 4);
  int2* edata = (int2*)alloc((size_t)E * 8);
  int* bsum   = (int*)alloc(64 * 4);
  int* boff   = (int*)alloc(64 * 4);
  ushort* Wh0 = (ushort*)alloc((size_t)1024 * HID * 2);
  ushort* Wl0 = (ushort*)alloc((size_t)1024 * HID * 2);
  ushort* Wh1 = (ushort*)alloc((size_t)HID * HID * 2);
  ushort* Wlo1 = (ushort*)alloc((size_t)HID * HID * 2);
  ushort* Wh2 = (ushort*)alloc((size_t)HID * HID * 2);
  ushort* Wlo2 = (ushort*)alloc((size_t)HID * HID * 2);
  float* gmax = (float*)alloc(NGRAPH * HID * 4);
  float* gsum = (float*)alloc(NGRAPH * HID * 4);
  int* gcnt   = (int*)alloc(NGRAPH * 4);

  hipMemsetAsync(cnt, 0, (size_t)N * 4, stream);
  hipMemsetAsync(fillc, 0, (size_t)N * 4, stream);
  hipMemsetAsync(gmax, 0, NGRAPH * HID * 4, stream);
  hipMemsetAsync(gsum, 0, NGRAPH * HID * 4, stream);
  hipMemsetAsync(gcnt, 0, NGRAPH * 4, stream);

  // weight splits (tiny)
  k_wsplit<<<(1024 * HID + 255) / 256, 256, 0, stream>>>(W0, Wh0, Wl0, 1024);
  k_wsplit<<<(HID * HID + 255) / 256, 256, 0, stream>>>(W1, Wh1, Wlo1, HID);
  k_wsplit<<<(HID * HID + 255) / 256, 256, 0, stream>>>(W2, Wh2, Wlo2, HID);

  // CSR build
  k_count<<<(E + 255) / 256, 256, 0, stream>>>(dstv, cnt, E);
  k_scan1<<<nb, 256, 0, stream>>>(cnt, bsum, N);
  k_scan2<<<1, 64, 0, stream>>>(bsum, boff, off, nb, N);
  k_scan3<<<nb, 256, 0, stream>>>(cnt, boff, off, dinv, N);
  k_fill<<<(E + 255) / 256, 256, 0, stream>>>(srcv, dstv, off, dinv, fillc, edata, E);

  const int gblk = (N + 127) / 128;
  const int ablk = (N + 3) / 4;
  // layer 0: 1024 -> 128
  k_gemm2<1024><<<gblk, 256, 0, stream>>>(x, Wh0, Wl0, xh, N);
  k_agg16<<<ablk, 256, 0, stream>>>(xh, dinv, off, edata, b0, bufB, N);
  // layer 1
  k_gemm2<HID><<<gblk, 256, 0, stream>>>(bufB, Wh1, Wlo1, xh, N);
  k_agg16<<<ablk, 256, 0, stream>>>(xh, dinv, off, edata, b1, bufB, N);
  // layer 2
  k_gemm2<HID><<<gblk, 256, 0, stream>>>(bufB, Wh2, Wlo2, xh, N);
  k_agg16<<<ablk, 256, 0, stream>>>(xh, dinv, off, edata, b2, bufB, N);

  // pooling + head
  k_gcnt<<<(N + 255) / 256, 256, 0, stream>>>(bat, gcnt, N);
  k_pool<<<(N + 127) / 128, 128, 0, stream>>>(bufB, bat, gmax, gsum, N);
  k_mlp<<<1, 256, 0, stream>>>(gmax, gsum, gcnt, Wl1, bl1, Wl2, bl2, Wl3, bl3, out);
}

// Round 8
// 370.583 us; speedup vs baseline: 1.1648x; 1.0571x over previous
//
#include <hip/hip_runtime.h>
#include <math.h>

#define HID 128
#define NGRAPH 4

typedef int idx_t;
typedef float f32x4 __attribute__((ext_vector_type(4)));
typedef _Float16 h8 __attribute__((ext_vector_type(8)));

// swizzled element offset into a [rows][32] fp16 LDS tile (16B slots)
__device__ inline int sw(int row, int slot) {
  return (row << 5) + ((slot ^ ((row >> 1) & 3)) << 3);
}

// ---------------- degree histogram ----------------
__global__ __launch_bounds__(256) void k_count(const idx_t* __restrict__ dst,
                                               int* __restrict__ cnt, int E) {
  int e = blockIdx.x * 256 + threadIdx.x;
  if (e < E) atomicAdd(&cnt[dst[e]], 1);
}

// ---------------- hierarchical exclusive scan ----------------
#define SC 1024
__global__ __launch_bounds__(256) void k_scan1(const int* __restrict__ cnt,
                                               int* __restrict__ bsum, int n) {
  __shared__ int sh[256];
  int base = blockIdx.x * SC + threadIdx.x * 4;
  int s = 0;
#pragma unroll
  for (int j = 0; j < 4; ++j) { int i = base + j; if (i < n) s += cnt[i]; }
  sh[threadIdx.x] = s;
  __syncthreads();
  for (int o = 128; o > 0; o >>= 1) {
    if (threadIdx.x < o) sh[threadIdx.x] += sh[threadIdx.x + o];
    __syncthreads();
  }
  if (threadIdx.x == 0) bsum[blockIdx.x] = sh[0];
}

__global__ __launch_bounds__(64) void k_scan2(const int* __restrict__ bsum,
                                              int* __restrict__ boff,
                                              int* __restrict__ off, int nb, int n) {
  int lane = threadIdx.x;
  int v = (lane < nb) ? bsum[lane] : 0;
  for (int d = 1; d < 64; d <<= 1) {
    int t = __shfl_up(v, d);
    if (lane >= d) v += t;
  }
  int ex = __shfl_up(v, 1);
  if (lane == 0) ex = 0;
  if (lane < nb) boff[lane] = ex;
  if (lane == nb - 1) off[n] = v;
}

__global__ __launch_bounds__(256) void k_scan3(const int* __restrict__ cnt,
                                               const int* __restrict__ boff,
                                               int* __restrict__ off,
                                               float* __restrict__ dinv, int n) {
  __shared__ int sh[256];
  int base = blockIdx.x * SC + threadIdx.x * 4;
  int c[4];
  int s = 0;
#pragma unroll
  for (int j = 0; j < 4; ++j) {
    int i = base + j;
    c[j] = (i < n) ? cnt[i] : 0;
    s += c[j];
  }
  sh[threadIdx.x] = s;
  __syncthreads();
  for (int o = 1; o < 256; o <<= 1) {
    int t = (threadIdx.x >= (unsigned)o) ? sh[threadIdx.x - o] : 0;
    __syncthreads();
    sh[threadIdx.x] += t;
    __syncthreads();
  }
  int ex = sh[threadIdx.x] - s + boff[blockIdx.x];
#pragma unroll
  for (int j = 0; j < 4; ++j) {
    int i = base + j;
    if (i < n) {
      off[i] = ex;
      dinv[i] = 1.0f / sqrtf((float)c[j] + 1.0f);
      ex += c[j];
    }
  }
}

// ---------------- CSR fill: packed (src, weight) per edge ----------------
__global__ __launch_bounds__(256) void k_fill(const idx_t* __restrict__ src,
                                              const idx_t* __restrict__ dst,
                                              const int* __restrict__ off,
                                              const float* __restrict__ dinv,
                                              int* __restrict__ fillc,
                                              int2* __restrict__ edata, int E) {
  int e = blockIdx.x * 256 + threadIdx.x;
  if (e < E) {
    int s = src[e], d = dst[e];
    int p = atomicAdd(&fillc[d], 1);
    float w = dinv[s] * dinv[d];
    edata[off[d] + p] = make_int2(s, __float_as_int(w));
  }
}

// ---------------- W split: fp32 [K][128] -> fp16 hi/lo transposed [128][K] --
__global__ __launch_bounds__(256) void k_wsplit(const float* __restrict__ W,
                                                _Float16* __restrict__ Wh,
                                                _Float16* __restrict__ Wl, int K) {
  int i = blockIdx.x * 256 + threadIdx.x;
  if (i >= K * HID) return;
  int k = i >> 7, n = i & 127;
  float f = W[i];
  _Float16 h = (_Float16)f;
  Wh[(size_t)n * K + k] = h;
  Wl[(size_t)n * K + k] = (_Float16)(f - (float)h);
}

// ---------------- pipelined split-fp16 MFMA GEMM ---------------------------
// Y16[M][128] = X[M][K] @ W[K][128].
// F32 input: A split to fp16 hi/lo in regs, 3 MFMA passes (err ~2^-22).
// F16 input: A exact, B split, 2 MFMA passes.
// BM=64 (4 waves x 16 rows), B double-buffered in LDS, 1 barrier/step.
// Requires K % 64 == 0.
template <int K, bool F32>
__global__ __launch_bounds__(256) void k_gemm3(const void* __restrict__ Xv,
                                               const _Float16* __restrict__ Wh,
                                               const _Float16* __restrict__ Wl,
                                               _Float16* __restrict__ Y16, int M) {
  __shared__ __align__(16) _Float16 BhL[2][128 * 32];
  __shared__ __align__(16) _Float16 BlL[2][128 * 32];
  const int tid = threadIdx.x;
  const int wid = tid >> 6, lane = tid & 63;
  const int lrow = lane & 15, kg = lane >> 4;
  const int row0 = blockIdx.x * 64;
  const int r = row0 + wid * 16 + lrow;
  const int rc = (r < M) ? r : 0;          // clamp: row 0 is always valid
  const float* xf = (const float*)Xv + (size_t)rc * K + kg * 8;
  const _Float16* xg = (const _Float16*)Xv + (size_t)rc * K + kg * 8;
  // B staging: thread covers col c0 and c0+64, slot s0
  const int c0 = tid >> 2, s0 = tid & 3;
  const int c1 = 64 + c0;
  const _Float16* wh0 = Wh + (size_t)c0 * K + s0 * 8;
  const _Float16* wh1 = Wh + (size_t)c1 * K + s0 * 8;
  const _Float16* wl0 = Wl + (size_t)c0 * K + s0 * 8;
  const _Float16* wl1 = Wl + (size_t)c1 * K + s0 * 8;
  const int d0 = sw(c0, s0), d1 = sw(c1, s0);

  f32x4 acc[8] = {};
  float4 aA0, aA1, aB0, aB1;   // F32 A regs (two pipeline stages)
  h8 gA, gB;                   // F16 A regs
  h8 bA0, bA1, bA2, bA3, bB0, bB1, bB2, bB3;

#define LOAD_A0(k0)                                                       \
  { if (F32) { aA0 = *(const float4*)(xf + (k0));                         \
               aA1 = *(const float4*)(xf + (k0) + 4); }                   \
    else gA = *(const h8*)(xg + (k0)); }
#define LOAD_A1(k0)                                                       \
  { if (F32) { aB0 = *(const float4*)(xf + (k0));                         \
               aB1 = *(const float4*)(xf + (k0) + 4); }                   \
    else gB = *(const h8*)(xg + (k0)); }
#define LOAD_B(k0, b0, b1, b2, b3)                                        \
  { b0 = *(const h8*)(wh0 + (k0)); b1 = *(const h8*)(wh1 + (k0));         \
    b2 = *(const h8*)(wl0 + (k0)); b3 = *(const h8*)(wl1 + (k0)); }
#define WRITE_B(buf, b0, b1, b2, b3)                                      \
  { *(h8*)&BhL[buf][d0] = b0; *(h8*)&BhL[buf][d1] = b1;                   \
    *(h8*)&BlL[buf][d0] = b2; *(h8*)&BlL[buf][d1] = b3; }
#define CONV(v0, v1, g, ah, al)                                           \
  { if (F32) {                                                            \
      float tf[8] = {v0.x, v0.y, v0.z, v0.w, v1.x, v1.y, v1.z, v1.w};     \
      _Pragma("unroll")                                                   \
      for (int j = 0; j < 8; ++j) {                                       \
        _Float16 hh = (_Float16)tf[j];                                    \
        ah[j] = hh; al[j] = (_Float16)(tf[j] - (float)hh);                \
      }                                                                   \
    } else ah = g; }
#define MFMA_STEP(buf, ah, al)                                            \
  { _Pragma("unroll")                                                     \
    for (int ni = 0; ni < 8; ++ni) {                                      \
      int c = ni * 16 + lrow;                                             \
      h8 bh = *(const h8*)&BhL[buf][sw(c, kg)];                           \
      h8 bl = *(const h8*)&BlL[buf][sw(c, kg)];                           \
      acc[ni] = __builtin_amdgcn_mfma_f32_16x16x32_f16(ah, bh, acc[ni], 0, 0, 0); \
      if (F32)                                                            \
        acc[ni] = __builtin_amdgcn_mfma_f32_16x16x32_f16(al, bh, acc[ni], 0, 0, 0); \
      acc[ni] = __builtin_amdgcn_mfma_f32_16x16x32_f16(ah, bl, acc[ni], 0, 0, 0); \
    } }

  // prologue
  LOAD_A0(0);
  LOAD_B(0, bA0, bA1, bA2, bA3);
  WRITE_B(0, bA0, bA1, bA2, bA3);
  if (K > 32) {
    LOAD_A1(32);
    LOAD_B(32, bB0, bB1, bB2, bB3);
  }
  __syncthreads();

  for (int k0 = 0; k0 < K; k0 += 64) {
    {  // even: compute buf0 (k0); stage k0+32 -> buf1; load k0+64
      if (k0 + 32 < K) WRITE_B(1, bB0, bB1, bB2, bB3);
      h8 ah, al;
      CONV(aA0, aA1, gA, ah, al);
      if (k0 + 64 < K) {
        LOAD_A0(k0 + 64);
        LOAD_B(k0 + 64, bA0, bA1, bA2, bA3);
      }
      MFMA_STEP(0, ah, al);
      __syncthreads();
    }
    if (k0 + 32 >= K) break;
    {  // odd: compute buf1 (k0+32); stage k0+64 -> buf0; load k0+96
      if (k0 + 96 < K) WRITE_B(0, bA0, bA1, bA2, bA3);
      h8 ah, al;
      CONV(aB0, aB1, gB, ah, al);
      if (k0 + 96 < K) {
        LOAD_A1(k0 + 96);
        LOAD_B(k0 + 96, bB0, bB1, bB2, bB3);
      }
      MFMA_STEP(1, ah, al);
      __syncthreads();
    }
  }
  // epilogue: C frag row=(lane>>4)*4+reg, col=lane&15
#pragma unroll
  for (int ni = 0; ni < 8; ++ni)
#pragma unroll
    for (int rr = 0; rr < 4; ++rr) {
      int grow = row0 + wid * 16 + kg * 4 + rr;
      if (grow < M)
        Y16[(size_t)grow * HID + ni * 16 + lrow] = (_Float16)acc[ni][rr];
    }
#undef LOAD_A0
#undef LOAD_A1
#undef LOAD_B
#undef WRITE_B
#undef CONV
#undef MFMA_STEP
}

// ---------------- gather-aggregate (fp16) + bias + ReLU --------------------
// One wave per node; 8 groups of 8 lanes; each lane covers 16 features (32B).
// 8 neighbor rows in flight per wave-iteration. fp32 accumulate, fp16 out.
__global__ __launch_bounds__(256) void k_agg16(const _Float16* __restrict__ xh,
                                               const float* __restrict__ dinv,
                                               const int* __restrict__ off,
                                               const int2* __restrict__ edata,
                                               const float* __restrict__ bias,
                                               _Float16* __restrict__ hout, int n) {
  int v = blockIdx.x * 4 + (threadIdx.x >> 6);
  if (v >= n) return;
  int lane = threadIdx.x & 63;
  int grp = lane >> 3, gl = lane & 7;
  int fb = gl * 16;
  float acc[16] = {0.f, 0.f, 0.f, 0.f, 0.f, 0.f, 0.f, 0.f,
                   0.f, 0.f, 0.f, 0.f, 0.f, 0.f, 0.f, 0.f};
  int j0 = off[v], j1 = off[v + 1];
  for (int j = j0 + grp; j < j1; j += 8) {
    int2 e = edata[j];
    float w = __int_as_float(e.y);
    h8 m0 = *(const h8*)&xh[(size_t)e.x * HID + fb];
    h8 m1 = *(const h8*)&xh[(size_t)e.x * HID + fb + 8];
#pragma unroll
    for (int q = 0; q < 8; ++q) {
      acc[q] = fmaf(w, (float)m0[q], acc[q]);
      acc[8 + q] = fmaf(w, (float)m1[q], acc[8 + q]);
    }
  }
#pragma unroll
  for (int q = 0; q < 16; ++q) {
    acc[q] += __shfl_xor(acc[q], 8);
    acc[q] += __shfl_xor(acc[q], 16);
    acc[q] += __shfl_xor(acc[q], 32);
  }
  if (grp == 0) {
    float dv = dinv[v], dv2 = dv * dv;
    h8 s0 = *(const h8*)&xh[(size_t)v * HID + fb];
    h8 s1 = *(const h8*)&xh[(size_t)v * HID + fb + 8];
    h8 o0, o1;
#pragma unroll
    for (int q = 0; q < 8; ++q) {
      float a0 = fmaxf(fmaf(dv2, (float)s0[q], acc[q]) + bias[fb + q], 0.f);
      float a1 = fmaxf(fmaf(dv2, (float)s1[q], acc[8 + q]) + bias[fb + 8 + q], 0.f);
      o0[q] = (_Float16)a0;
      o1[q] = (_Float16)a1;
    }
    *(h8*)&hout[(size_t)v * HID + fb] = o0;
    *(h8*)&hout[(size_t)v * HID + fb + 8] = o1;
  }
}

// ---------------- per-graph node counts ----------------
__global__ __launch_bounds__(256) void k_gcnt(const idx_t* __restrict__ batch,
                                              int* __restrict__ gcnt, int n) {
  __shared__ int h[NGRAPH];
  int tid = threadIdx.x;
  if (tid < NGRAPH) h[tid] = 0;
  __syncthreads();
  int i = blockIdx.x * 256 + tid;
  if (i < n) atomicAdd(&h[batch[i]], 1);
  __syncthreads();
  if (tid < NGRAPH && h[tid]) atomicAdd(&gcnt[tid], h[tid]);
}

// ---------------- segment max+sum pooling (fp16 input, batch sorted) -------
__global__ __launch_bounds__(128) void k_pool(const _Float16* __restrict__ h,
                                              const idx_t* __restrict__ batch,
                                              float* __restrict__ gmax,
                                              float* __restrict__ gsum, int n) {
  int f = threadIdx.x;
  int v0 = blockIdx.x * 128;
  int cur = -1;
  float mx = 0.f, sm = 0.f;
  for (int i = 0; i < 128; ++i) {
    int v = v0 + i;
    if (v >= n) break;
    int g = batch[v];
    if (g != cur) {
      if (cur >= 0) {
        atomicMax((int*)&gmax[cur * HID + f], __float_as_int(mx));  // h>=0
        atomicAdd(&gsum[cur * HID + f], sm);
      }
      cur = g; mx = 0.f; sm = 0.f;
    }
    float val = (float)h[(size_t)v * HID + f];
    mx = fmaxf(mx, val);
    sm += val;
  }
  if (cur >= 0) {
    atomicMax((int*)&gmax[cur * HID + f], __float_as_int(mx));
    atomicAdd(&gsum[cur * HID + f], sm);
  }
}

// ---------------- tiny MLP head (one block) ----------------
__global__ __launch_bounds__(256) void k_mlp(const float* __restrict__ gmax,
                                             const float* __restrict__ gsum,
                                             const int* __restrict__ gcnt,
                                             const float* __restrict__ Wl1,
                                             const float* __restrict__ bl1,
                                             const float* __restrict__ Wl2,
                                             const float* __restrict__ bl2,
                                             const float* __restrict__ Wl3,
                                             const float* __restrict__ bl3,
                                             float* __restrict__ out) {
  __shared__ float G[NGRAPH][2 * HID];
  __shared__ float H1[NGRAPH][HID];
  __shared__ float H2[NGRAPH][HID / 2];
  int t = threadIdx.x;
  for (int i = t; i < NGRAPH * 2 * HID; i += 256) {
    int gi = i >> 8, j = i & 255;
    float val;
    if (j < HID) val = gmax[gi * HID + j];
    else val = gsum[gi * HID + (j - HID)] / fmaxf((float)gcnt[gi], 1.0f);
    G[gi][j] = val;
  }
  __syncthreads();
  for (int i = t; i < NGRAPH * HID; i += 256) {
    int gi = i >> 7, j = i & 127;
    float a = bl1[j];
    for (int k = 0; k < 2 * HID; ++k) a = fmaf(G[gi][k], Wl1[k * HID + j], a);
    H1[gi][j] = fmaxf(a, 0.f);
  }
  __syncthreads();
  {
    int gi = t >> 6, j = t & 63;
    float a = bl2[j];
    for (int k = 0; k < HID; ++k) a = fmaf(H1[gi][k], Wl2[k * 64 + j], a);
    H2[gi][j] = fmaxf(a, 0.f);
  }
  __syncthreads();
  if (t < NGRAPH) {
    float a = bl3[0];
    for (int k = 0; k < 64; ++k) a = fmaf(H2[t][k], Wl3[k], a);
    out[t] = fminf(a, 5.0f);
  }
}

extern "C" void kernel_launch(void* const* d_in, const int* in_sizes, int n_in,
                              void* d_out, int out_size, void* d_ws, size_t ws_size,
                              hipStream_t stream) {
  const float* x   = (const float*)d_in[0];
  const idx_t* ei  = (const idx_t*)d_in[1];
  const idx_t* bat = (const idx_t*)d_in[2];
  const float* W0 = (const float*)d_in[3];  const float* b0 = (const float*)d_in[4];
  const float* W1 = (const float*)d_in[5];  const float* b1 = (const float*)d_in[6];
  const float* W2 = (const float*)d_in[7];  const float* b2 = (const float*)d_in[8];
  const float* Wl1 = (const float*)d_in[9];  const float* bl1 = (const float*)d_in[10];
  const float* Wl2 = (const float*)d_in[11]; const float* bl2 = (const float*)d_in[12];
  const float* Wl3 = (const float*)d_in[13]; const float* bl3 = (const float*)d_in[14];
  float* out = (float*)d_out;

  const int N = in_sizes[2];
  const int E = in_sizes[1] / 2;
  const idx_t* srcv = ei;
  const idx_t* dstv = ei + E;
  const int nb = (N + SC - 1) / SC;

  char* ws = (char*)d_ws;
  size_t o = 0;
  auto alloc = [&](size_t bytes) -> void* {
    void* p = ws + o;
    o = (o + bytes + 255) & ~(size_t)255;
    return p;
  };
  _Float16* xh  = (_Float16*)alloc((size_t)N * HID * 2);  // GEMM out (gathered)
  _Float16* h16 = (_Float16*)alloc((size_t)N * HID * 2);  // agg out
  float* dinv = (float*)alloc((size_t)N * 4);
  int* cnt    = (int*)alloc((size_t)N * 4);
  int* off    = (int*)alloc((size_t)(N + 1) * 4);
  int* fillc  = (int*)alloc((size_t)N * 4);
  int2* edata = (int2*)alloc((size_t)E * 8);
  int* bsum   = (int*)alloc(64 * 4);
  int* boff   = (int*)alloc(64 * 4);
  _Float16* Wh0 = (_Float16*)alloc((size_t)1024 * HID * 2);
  _Float16* Wl0 = (_Float16*)alloc((size_t)1024 * HID * 2);
  _Float16* Wh1 = (_Float16*)alloc((size_t)HID * HID * 2);
  _Float16* Wlo1 = (_Float16*)alloc((size_t)HID * HID * 2);
  _Float16* Wh2 = (_Float16*)alloc((size_t)HID * HID * 2);
  _Float16* Wlo2 = (_Float16*)alloc((size_t)HID * HID * 2);
  float* gmax = (float*)alloc(NGRAPH * HID * 4);
  float* gsum = (float*)alloc(NGRAPH * HID * 4);
  int* gcnt   = (int*)alloc(NGRAPH * 4);

  hipMemsetAsync(cnt, 0, (size_t)N * 4, stream);
  hipMemsetAsync(fillc, 0, (size_t)N * 4, stream);
  hipMemsetAsync(gmax, 0, NGRAPH * HID * 4, stream);
  hipMemsetAsync(gsum, 0, NGRAPH * HID * 4, stream);
  hipMemsetAsync(gcnt, 0, NGRAPH * 4, stream);

  // weight splits (tiny)
  k_wsplit<<<(1024 * HID + 255) / 256, 256, 0, stream>>>(W0, Wh0, Wl0, 1024);
  k_wsplit<<<(HID * HID + 255) / 256, 256, 0, stream>>>(W1, Wh1, Wlo1, HID);
  k_wsplit<<<(HID * HID + 255) / 256, 256, 0, stream>>>(W2, Wh2, Wlo2, HID);

  // CSR build
  k_count<<<(E + 255) / 256, 256, 0, stream>>>(dstv, cnt, E);
  k_scan1<<<nb, 256, 0, stream>>>(cnt, bsum, N);
  k_scan2<<<1, 64, 0, stream>>>(bsum, boff, off, nb, N);
  k_scan3<<<nb, 256, 0, stream>>>(cnt, boff, off, dinv, N);
  k_fill<<<(E + 255) / 256, 256, 0, stream>>>(srcv, dstv, off, dinv, fillc, edata, E);

  const int gblk = (N + 63) / 64;   // 782 blocks
  const int ablk = (N + 3) / 4;
  // layer 0: 1024 -> 128 (fp32 in, 3-pass)
  k_gemm3<1024, true><<<gblk, 256, 0, stream>>>(x, Wh0, Wl0, xh, N);
  k_agg16<<<ablk, 256, 0, stream>>>(xh, dinv, off, edata, b0, h16, N);
  // layer 1 (fp16 in, 2-pass)
  k_gemm3<HID, false><<<gblk, 256, 0, stream>>>(h16, Wh1, Wlo1, xh, N);
  k_agg16<<<ablk, 256, 0, stream>>>(xh, dinv, off, edata, b1, h16, N);
  // layer 2
  k_gemm3<HID, false><<<gblk, 256, 0, stream>>>(h16, Wh2, Wlo2, xh, N);
  k_agg16<<<ablk, 256, 0, stream>>>(xh, dinv, off, edata, b2, h16, N);

  // pooling + head
  k_gcnt<<<(N + 255) / 256, 256, 0, stream>>>(bat, gcnt, N);
  k_pool<<<(N + 127) / 128, 128, 0, stream>>>(h16, bat, gmax, gsum, N);
  k_mlp<<<1, 256, 0, stream>>>(gmax, gsum, gcnt, Wl1, bl1, Wl2, bl2, Wl3, bl3, out);
}